// Round 1
// baseline (622.528 us; speedup 1.0000x reference)
//
#include <hip/hip_runtime.h>
#include <hip/hip_bf16.h>
#include <stdint.h>

static constexpr int ND = 8192;

typedef __attribute__((ext_vector_type(8))) short bf16x8;
typedef __attribute__((ext_vector_type(4))) float f32x4;

#define GLOBAL_AS __attribute__((address_space(1)))
#define LDS_AS __attribute__((address_space(3)))

__device__ __forceinline__ void gld_lds16(const void* g, void* l) {
    __builtin_amdgcn_global_load_lds((const GLOBAL_AS void*)g, (LDS_AS void*)l, 16, 0, 0);
}

__device__ __forceinline__ unsigned short f2bf(float x) {
    union { float f; uint32_t u; } v; v.f = x;
    uint32_t u = v.u;
    uint32_t r = (u + 0x7fffu + ((u >> 16) & 1u)) >> 16;
    return (unsigned short)r;
}

// ---------------- pre-pass 1: Aw[i][k] = (k>=i) ? bf16(A[i][k]) : 0 ----------------
__global__ void conv_a(const float* __restrict__ A, unsigned short* __restrict__ Aw) {
    uint32_t g = blockIdx.x * 256u + threadIdx.x;   // 8-element group id
    int i  = (int)(g >> 10);                         // ND/8 = 1024 groups per row
    int k0 = (int)(g & 1023u) << 3;
    const float* src = A + (size_t)i * ND + k0;
    float4 lo = *(const float4*)src;
    float4 hi = *(const float4*)(src + 4);
    float vals[8] = {lo.x, lo.y, lo.z, lo.w, hi.x, hi.y, hi.z, hi.w};
    unsigned short out[8];
#pragma unroll
    for (int e = 0; e < 8; ++e) {
        int k = k0 + e;
        out[e] = (k >= i) ? f2bf(vals[e]) : (unsigned short)0;
    }
    *(uint4*)(Aw + (size_t)i * ND + k0) = *(const uint4*)out;
}

// ------------- pre-pass 2: Bt[j][k] = (k<=j) ? bf16(B[k][j]) : 0 (transpose) -------------
__global__ void conv_bt(const float* __restrict__ B, unsigned short* __restrict__ Bt) {
    __shared__ float tile[64][65];
    int tk = blockIdx.x, tj = blockIdx.y;
    int t = threadIdx.x;
    int k0 = tk * 64, j0 = tj * 64;

    if (k0 > j0 + 63) {  // entire tile has k > j -> zeros
        int jl = t >> 4;
        int kl = (t & 15) * 4;
#pragma unroll
        for (int r = 0; r < 4; ++r) {
            int j = j0 + jl + r * 16;
            *(uint2*)(Bt + (size_t)j * ND + k0 + kl) = make_uint2(0u, 0u);
        }
        return;
    }
    {   // load phase: coalesced in j
        int kl  = t >> 4;
        int jl4 = (t & 15) * 4;
#pragma unroll
        for (int r = 0; r < 4; ++r) {
            int k = k0 + kl + r * 16;
            float4 v = *(const float4*)(B + (size_t)k * ND + j0 + jl4);
            tile[kl + r * 16][jl4 + 0] = v.x;
            tile[kl + r * 16][jl4 + 1] = v.y;
            tile[kl + r * 16][jl4 + 2] = v.z;
            tile[kl + r * 16][jl4 + 3] = v.w;
        }
    }
    __syncthreads();
    {   // store phase: coalesced in k
        int jl  = t >> 4;
        int kl4 = (t & 15) * 4;
#pragma unroll
        for (int r = 0; r < 4; ++r) {
            int j = j0 + jl + r * 16;
            unsigned short o[4];
#pragma unroll
            for (int e = 0; e < 4; ++e) {
                int k = k0 + kl4 + e;
                float v = tile[kl4 + e][jl + r * 16];
                o[e] = (k <= j) ? f2bf(v) : (unsigned short)0;
            }
            *(uint2*)(Bt + (size_t)j * ND + k0 + kl4) = *(const uint2*)o;
        }
    }
}

// ---------------- main GEMM: C = Aw @ Bt^T, upper-triangular tiles only ----------------
__global__ __launch_bounds__(256) void gemm_tri(const unsigned short* __restrict__ Aw,
                                                const unsigned short* __restrict__ Bt,
                                                float* __restrict__ C) {
    int tj = blockIdx.x, ti = blockIdx.y;
    int t = threadIdx.x;

    if (tj < ti) {  // strictly-lower tile: write zeros (d_out is poisoned)
        int row = t >> 1, cb = (t & 1) * 64;
        float* p = C + (size_t)(ti * 128 + row) * ND + tj * 128 + cb;
        float4 z = {0.f, 0.f, 0.f, 0.f};
#pragma unroll
        for (int q = 0; q < 16; ++q) *(float4*)(p + q * 4) = z;
        return;
    }

    __shared__ __align__(16) unsigned short As[128 * 64];
    __shared__ __align__(16) unsigned short Bs[128 * 64];

    int lane = t & 63;
    int w    = t >> 6;           // wave 0..3
    int wr   = w >> 1, wc = w & 1;

    // staging: wave w stages rows {q*32 + w*8 .. +8} of each 128x64 tile
    const unsigned short* gA0 =
        Aw + (size_t)(ti * 128 + w * 8 + (lane >> 3)) * ND + (lane & 7) * 8;
    const unsigned short* gB0 =
        Bt + (size_t)(tj * 128 + w * 8 + (lane >> 3)) * ND + (lane & 7) * 8;
    unsigned short* lA = As + w * 512 + lane * 8;
    unsigned short* lB = Bs + w * 512 + lane * 8;

    f32x4 acc[4][4];
#pragma unroll
    for (int m = 0; m < 4; ++m)
#pragma unroll
        for (int n = 0; n < 4; ++n) acc[m][n] = (f32x4){0.f, 0.f, 0.f, 0.f};

    int nk = (tj - ti + 1) * 2;        // BK=64 steps over k in [ti*128, (tj+1)*128)
    int kstart = ti * 128;

    for (int kt = 0; kt < nk; ++kt) {
        int kbase = kstart + kt * 64;
#pragma unroll
        for (int q = 0; q < 4; ++q) {
            gld_lds16(gA0 + kbase + (size_t)(q * 32) * ND, lA + q * 2048);
            gld_lds16(gB0 + kbase + (size_t)(q * 32) * ND, lB + q * 2048);
        }
        __syncthreads();

#pragma unroll
        for (int kk = 0; kk < 2; ++kk) {
            int klane = kk * 32 + (lane >> 4) * 8;
            bf16x8 af[4], bfr[4];
#pragma unroll
            for (int m = 0; m < 4; ++m) {
                int row = wr * 64 + m * 16 + (lane & 15);
                af[m] = *(const bf16x8*)(As + row * 64 + klane);
            }
#pragma unroll
            for (int n = 0; n < 4; ++n) {
                int col = wc * 64 + n * 16 + (lane & 15);
                bfr[n] = *(const bf16x8*)(Bs + col * 64 + klane);
            }
#pragma unroll
            for (int m = 0; m < 4; ++m)
#pragma unroll
                for (int n = 0; n < 4; ++n)
                    acc[m][n] = __builtin_amdgcn_mfma_f32_16x16x32_bf16(
                        af[m], bfr[n], acc[m][n], 0, 0, 0);
        }
        __syncthreads();
    }

    // epilogue: C/D layout col=lane&15, row=(lane>>4)*4+e  [m89-verified]
#pragma unroll
    for (int m = 0; m < 4; ++m) {
#pragma unroll
        for (int n = 0; n < 4; ++n) {
            int row = ti * 128 + wr * 64 + m * 16 + (lane >> 4) * 4;
            int col = tj * 128 + wc * 64 + n * 16 + (lane & 15);
            f32x4 v = acc[m][n];
#pragma unroll
            for (int e = 0; e < 4; ++e)
                C[(size_t)(row + e) * ND + col] = v[e];
        }
    }
}

// ---------------- fallback (only if ws_size < 256 MiB): slow but correct ----------------
__global__ void tri_naive(const float* __restrict__ A, const float* __restrict__ B,
                          float* __restrict__ C) {
    int j = blockIdx.x * 64 + (threadIdx.x & 63);
    int i = blockIdx.y * 4 + (threadIdx.x >> 6);
    float s = 0.f;
    if (j >= i) {
        for (int k = i; k <= j; ++k) s += A[(size_t)i * ND + k] * B[(size_t)k * ND + j];
        C[(size_t)i * ND + j] = s;
    } else {
        C[(size_t)i * ND + j] = 0.f;
    }
}

extern "C" void kernel_launch(void* const* d_in, const int* in_sizes, int n_in,
                              void* d_out, int out_size, void* d_ws, size_t ws_size,
                              hipStream_t stream) {
    (void)in_sizes; (void)n_in; (void)out_size;
    const float* A = (const float*)d_in[0];
    const float* B = (const float*)d_in[1];
    float* C = (float*)d_out;

    const size_t halfws = (size_t)ND * ND * sizeof(unsigned short);  // 128 MiB
    if (ws_size >= 2 * halfws) {
        unsigned short* Aw = (unsigned short*)d_ws;
        unsigned short* Bt = (unsigned short*)((char*)d_ws + halfws);

        conv_a<<<dim3(ND * (ND / 8) / 256), dim3(256), 0, stream>>>(A, Aw);
        conv_bt<<<dim3(ND / 64, ND / 64), dim3(256), 0, stream>>>(B, Bt);
        gemm_tri<<<dim3(ND / 128, ND / 128), dim3(256), 0, stream>>>(Aw, Bt, C);
    } else {
        tri_naive<<<dim3(ND / 64, ND / 4), dim3(256), 0, stream>>>(A, B, C);
    }
}

// Round 2
// 483.069 us; speedup vs baseline: 1.2887x; 1.2887x over previous
//
#include <hip/hip_runtime.h>
#include <hip/hip_bf16.h>
#include <stdint.h>

static constexpr int ND = 8192;

typedef __attribute__((ext_vector_type(8))) short bf16x8;
typedef __attribute__((ext_vector_type(4))) float f32x4;

#define GLOBAL_AS __attribute__((address_space(1)))
#define LDS_AS __attribute__((address_space(3)))

__device__ __forceinline__ void gld_lds16(const void* g, void* l) {
    __builtin_amdgcn_global_load_lds((const GLOBAL_AS void*)g, (LDS_AS void*)l, 16, 0, 0);
}

__device__ __forceinline__ unsigned short f2bf(float x) {
    union { float f; uint32_t u; } v; v.f = x;
    uint32_t u = v.u;
    uint32_t r = (u + 0x7fffu + ((u >> 16) & 1u)) >> 16;
    return (unsigned short)r;
}

// ---------------- pre-pass 1: Aw[i][k] = (k>=i) ? bf16(A[i][k]) : 0 ----------------
// Skips k-groups entirely below the diagonal 128-block (never read by GEMM).
__global__ void conv_a(const float* __restrict__ A, unsigned short* __restrict__ Aw) {
    uint32_t g = blockIdx.x * 256u + threadIdx.x;
    int i  = (int)(g >> 10);
    int k0 = (int)(g & 1023u) << 3;
    if (k0 + 8 <= (i & ~127)) return;          // never read: k < (i>>7)*128
    const float* src = A + (size_t)i * ND + k0;
    float4 lo = *(const float4*)src;
    float4 hi = *(const float4*)(src + 4);
    float vals[8] = {lo.x, lo.y, lo.z, lo.w, hi.x, hi.y, hi.z, hi.w};
    unsigned short out[8];
#pragma unroll
    for (int e = 0; e < 8; ++e) {
        int k = k0 + e;
        out[e] = (k >= i) ? f2bf(vals[e]) : (unsigned short)0;
    }
    *(uint4*)(Aw + (size_t)i * ND + k0) = *(const uint4*)out;
}

// ------------- pre-pass 2: Bt[j][k] = (k<=j) ? bf16(B[k][j]) : 0 (transpose) -------------
__global__ void conv_bt(const float* __restrict__ B, unsigned short* __restrict__ Bt) {
    __shared__ float tile[64][65];
    int tk = blockIdx.x, tj = blockIdx.y;
    int t = threadIdx.x;
    int k0 = tk * 64, j0 = tj * 64;

    if (k0 > j0 + 63) {                         // tile wholly above diagonal (k > j)
        if (tk >= 2 * (tj >> 1) + 2) return;    // beyond the 128-block: never read
        int jl = t >> 4;
        int kl = (t & 15) * 4;
#pragma unroll
        for (int r = 0; r < 4; ++r) {
            int j = j0 + jl + r * 16;
            *(uint2*)(Bt + (size_t)j * ND + k0 + kl) = make_uint2(0u, 0u);
        }
        return;
    }
    {   // load: coalesced in j
        int kl  = t >> 4;
        int jl4 = (t & 15) * 4;
#pragma unroll
        for (int r = 0; r < 4; ++r) {
            int k = k0 + kl + r * 16;
            float4 v = *(const float4*)(B + (size_t)k * ND + j0 + jl4);
            tile[kl + r * 16][jl4 + 0] = v.x;
            tile[kl + r * 16][jl4 + 1] = v.y;
            tile[kl + r * 16][jl4 + 2] = v.z;
            tile[kl + r * 16][jl4 + 3] = v.w;
        }
    }
    __syncthreads();
    {   // store: coalesced in k
        int jl  = t >> 4;
        int kl4 = (t & 15) * 4;
#pragma unroll
        for (int r = 0; r < 4; ++r) {
            int j = j0 + jl + r * 16;
            unsigned short o[4];
#pragma unroll
            for (int e = 0; e < 4; ++e) {
                int k = k0 + kl4 + e;
                float v = tile[kl4 + e][jl + r * 16];
                o[e] = (k <= j) ? f2bf(v) : (unsigned short)0;
            }
            *(uint2*)(Bt + (size_t)j * ND + k0 + kl4) = *(const uint2*)o;
        }
    }
}

// ---------------- coalesced zero-fill of strictly-lower 128x128 tiles ----------------
__global__ __launch_bounds__(256) void zero_lower(float* __restrict__ C) {
    int bid = blockIdx.x;                        // 0 .. 2015
    int ti = (int)((1.0f + sqrtf(8.0f * (float)bid + 1.0f)) * 0.5f);
    while (ti * (ti + 1) / 2 <= bid) ++ti;
    while (ti * (ti - 1) / 2 > bid) --ti;
    int tj = bid - ti * (ti - 1) / 2;            // ti in [1,63], tj < ti
    int t = threadIdx.x;
    float* base = C + (size_t)(ti * 128) * ND + tj * 128;
    float4 z = {0.f, 0.f, 0.f, 0.f};
#pragma unroll
    for (int it = 0; it < 16; ++it) {
        int row = it * 8 + (t >> 5);
        *(float4*)(base + (size_t)row * ND + (t & 31) * 4) = z;
    }
}

// ---------------- main GEMM: upper tiles only, LPT order, swizzled LDS ----------------
__global__ __launch_bounds__(256) void gemm_tri(const unsigned short* __restrict__ Aw,
                                                const unsigned short* __restrict__ Bt,
                                                float* __restrict__ C) {
    int bid = blockIdx.x;                        // 0 .. 2079, longest diagonal first
    int s = (int)((sqrtf(8.0f * (float)bid + 1.0f) - 1.0f) * 0.5f);
    while ((s + 1) * (s + 2) / 2 <= bid) ++s;
    while (s * (s + 1) / 2 > bid) --s;
    int ti = bid - s * (s + 1) / 2;
    int tj = ti + (63 - s);

    __shared__ __align__(16) unsigned short As[128 * 64];
    __shared__ __align__(16) unsigned short Bs[128 * 64];

    int t = threadIdx.x;
    int lane = t & 63;
    int w    = t >> 6;
    int wr   = w >> 1, wc = w & 1;

    // Staging with pre-swizzled GLOBAL source (rule 21 / m173): LDS dest linear,
    // source column-granule XORed by (row&7). row&7 == lane>>3 here.
    int swz_src = ((lane & 7) ^ (lane >> 3)) * 8;            // shorts within row
    const unsigned short* gA0 =
        Aw + (size_t)(ti * 128 + w * 8 + (lane >> 3)) * ND + swz_src;
    const unsigned short* gB0 =
        Bt + (size_t)(tj * 128 + w * 8 + (lane >> 3)) * ND + swz_src;
    unsigned short* lA = As + w * 512 + lane * 8;
    unsigned short* lB = Bs + w * 512 + lane * 8;

    f32x4 acc[4][4];
#pragma unroll
    for (int m = 0; m < 4; ++m)
#pragma unroll
        for (int n = 0; n < 4; ++n) acc[m][n] = (f32x4){0.f, 0.f, 0.f, 0.f};

    int nk = (tj - ti + 1) * 2;
    int kstart = ti * 128;
    int rsw = (lane & 7) * 8;                    // read-side XOR (shorts), = (row&7)*8

    for (int kt = 0; kt < nk; ++kt) {
        int kbase = kstart + kt * 64;
#pragma unroll
        for (int q = 0; q < 4; ++q) {
            gld_lds16(gA0 + kbase + (size_t)(q * 32) * ND, lA + q * 2048);
            gld_lds16(gB0 + kbase + (size_t)(q * 32) * ND, lB + q * 2048);
        }
        __syncthreads();

#pragma unroll
        for (int kk = 0; kk < 2; ++kk) {
            int klane = kk * 32 + (lane >> 4) * 8;
            int koff  = klane ^ rsw;             // swizzled read offset (shorts)
            bf16x8 af[4], bfr[4];
#pragma unroll
            for (int m = 0; m < 4; ++m) {
                int row = wr * 64 + m * 16 + (lane & 15);
                af[m] = *(const bf16x8*)(As + row * 64 + koff);
            }
#pragma unroll
            for (int n = 0; n < 4; ++n) {
                int col = wc * 64 + n * 16 + (lane & 15);
                bfr[n] = *(const bf16x8*)(Bs + col * 64 + koff);
            }
#pragma unroll
            for (int m = 0; m < 4; ++m)
#pragma unroll
                for (int n = 0; n < 4; ++n)
                    acc[m][n] = __builtin_amdgcn_mfma_f32_16x16x32_bf16(
                        af[m], bfr[n], acc[m][n], 0, 0, 0);
        }
        __syncthreads();
    }

    // epilogue: C/D layout col=lane&15, row=(lane>>4)*4+e
#pragma unroll
    for (int m = 0; m < 4; ++m) {
#pragma unroll
        for (int n = 0; n < 4; ++n) {
            int row = ti * 128 + wr * 64 + m * 16 + (lane >> 4) * 4;
            int col = tj * 128 + wc * 64 + n * 16 + (lane & 15);
            f32x4 v = acc[m][n];
#pragma unroll
            for (int e = 0; e < 4; ++e)
                C[(size_t)(row + e) * ND + col] = v[e];
        }
    }
}

// ---------------- fallback (only if ws too small): slow but correct ----------------
__global__ void tri_naive(const float* __restrict__ A, const float* __restrict__ B,
                          float* __restrict__ C) {
    int j = blockIdx.x * 64 + (threadIdx.x & 63);
    int i = blockIdx.y * 4 + (threadIdx.x >> 6);
    float s = 0.f;
    if (j >= i) {
        for (int k = i; k <= j; ++k) s += A[(size_t)i * ND + k] * B[(size_t)k * ND + j];
        C[(size_t)i * ND + j] = s;
    } else {
        C[(size_t)i * ND + j] = 0.f;
    }
}

extern "C" void kernel_launch(void* const* d_in, const int* in_sizes, int n_in,
                              void* d_out, int out_size, void* d_ws, size_t ws_size,
                              hipStream_t stream) {
    (void)in_sizes; (void)n_in; (void)out_size;
    const float* A = (const float*)d_in[0];
    const float* B = (const float*)d_in[1];
    float* C = (float*)d_out;

    const size_t halfws = (size_t)ND * ND * sizeof(unsigned short);  // 128 MiB
    if (ws_size >= 2 * halfws) {
        unsigned short* Aw = (unsigned short*)d_ws;
        unsigned short* Bt = (unsigned short*)((char*)d_ws + halfws);

        conv_a<<<dim3(ND * (ND / 8) / 256), dim3(256), 0, stream>>>(A, Aw);
        conv_bt<<<dim3(ND / 64, ND / 64), dim3(256), 0, stream>>>(B, Bt);
        zero_lower<<<dim3(2016), dim3(256), 0, stream>>>(C);
        gemm_tri<<<dim3(2080), dim3(256), 0, stream>>>(Aw, Bt, C);
    } else {
        tri_naive<<<dim3(ND / 64, ND / 4), dim3(256), 0, stream>>>(A, B, C);
    }
}

// Round 3
// 345.646 us; speedup vs baseline: 1.8011x; 1.3976x over previous
//
#include <hip/hip_runtime.h>
#include <hip/hip_bf16.h>
#include <stdint.h>

static constexpr int ND = 8192;

typedef __attribute__((ext_vector_type(8))) short bf16x8;
typedef __attribute__((ext_vector_type(4))) float f32x4;

#define GLOBAL_AS __attribute__((address_space(1)))
#define LDS_AS __attribute__((address_space(3)))

__device__ __forceinline__ void gld_lds16(const void* g, void* l) {
    __builtin_amdgcn_global_load_lds((const GLOBAL_AS void*)g, (LDS_AS void*)l, 16, 0, 0);
}

__device__ __forceinline__ unsigned short f2bf(float x) {
    union { float f; uint32_t u; } v; v.f = x;
    uint32_t u = v.u;
    uint32_t r = (u + 0x7fffu + ((u >> 16) & 1u)) >> 16;
    return (unsigned short)r;
}

// ---------------- pre-pass 1: Aw[i][k] = (k>=i) ? bf16(A[i][k]) : 0 ----------------
// Skip k below the 256-aligned diagonal block (never read by 256-tile GEMM).
__global__ void conv_a(const float* __restrict__ A, unsigned short* __restrict__ Aw) {
    uint32_t g = blockIdx.x * 256u + threadIdx.x;
    int i  = (int)(g >> 10);
    int k0 = (int)(g & 1023u) << 3;
    if (k0 + 8 <= (i & ~255)) return;          // never read: k < (i>>8)*256
    const float* src = A + (size_t)i * ND + k0;
    float4 lo = *(const float4*)src;
    float4 hi = *(const float4*)(src + 4);
    float vals[8] = {lo.x, lo.y, lo.z, lo.w, hi.x, hi.y, hi.z, hi.w};
    unsigned short out[8];
#pragma unroll
    for (int e = 0; e < 8; ++e) {
        int k = k0 + e;
        out[e] = (k >= i) ? f2bf(vals[e]) : (unsigned short)0;
    }
    *(uint4*)(Aw + (size_t)i * ND + k0) = *(const uint4*)out;
}

// ------------- pre-pass 2: Bt[j][k] = (k<=j) ? bf16(B[k][j]) : 0 (transpose) -------------
__global__ void conv_bt(const float* __restrict__ B, unsigned short* __restrict__ Bt) {
    __shared__ float tile[64][65];
    int tk = blockIdx.x, tj = blockIdx.y;
    int t = threadIdx.x;
    int k0 = tk * 64, j0 = tj * 64;

    if (k0 > j0 + 63) {                         // tile wholly above diagonal (k > j)
        if (tk >= ((tj >> 2) + 1) * 4) return;  // beyond the 256-block: never read
        int jl = t >> 4;
        int kl = (t & 15) * 4;
#pragma unroll
        for (int r = 0; r < 4; ++r) {
            int j = j0 + jl + r * 16;
            *(uint2*)(Bt + (size_t)j * ND + k0 + kl) = make_uint2(0u, 0u);
        }
        return;
    }
    {   // load: coalesced in j
        int kl  = t >> 4;
        int jl4 = (t & 15) * 4;
#pragma unroll
        for (int r = 0; r < 4; ++r) {
            int k = k0 + kl + r * 16;
            float4 v = *(const float4*)(B + (size_t)k * ND + j0 + jl4);
            tile[kl + r * 16][jl4 + 0] = v.x;
            tile[kl + r * 16][jl4 + 1] = v.y;
            tile[kl + r * 16][jl4 + 2] = v.z;
            tile[kl + r * 16][jl4 + 3] = v.w;
        }
    }
    __syncthreads();
    {   // store: coalesced in k
        int jl  = t >> 4;
        int kl4 = (t & 15) * 4;
#pragma unroll
        for (int r = 0; r < 4; ++r) {
            int j = j0 + jl + r * 16;
            unsigned short o[4];
#pragma unroll
            for (int e = 0; e < 4; ++e) {
                int k = k0 + kl4 + e;
                float v = tile[kl4 + e][jl + r * 16];
                o[e] = (k <= j) ? f2bf(v) : (unsigned short)0;
            }
            *(uint2*)(Bt + (size_t)j * ND + k0 + kl4) = *(const uint2*)o;
        }
    }
}

// ------ zero-fill strictly-lower 128x128 tiles NOT covered by diagonal 256-blocks ------
__global__ __launch_bounds__(256) void zero_lower(float* __restrict__ C) {
    int bid = blockIdx.x;                        // 0 .. 2015
    int ti = (int)((1.0f + sqrtf(8.0f * (float)bid + 1.0f)) * 0.5f);
    while (ti * (ti + 1) / 2 <= bid) ++ti;
    while (ti * (ti - 1) / 2 > bid) --ti;
    int tj = bid - ti * (ti - 1) / 2;            // ti in [1,63], tj < ti
    if ((ti >> 1) == (tj >> 1)) return;          // covered by diagonal 256-tile GEMM
    int t = threadIdx.x;
    float* base = C + (size_t)(ti * 128) * ND + tj * 128;
    float4 z = {0.f, 0.f, 0.f, 0.f};
#pragma unroll
    for (int it = 0; it < 16; ++it) {
        int row = it * 8 + (t >> 5);
        *(float4*)(base + (size_t)row * ND + (t & 31) * 4) = z;
    }
}

// ============ main GEMM: 256x256 tiles, 8-phase pipeline, upper tiles, LPT ============
#define BAR() __builtin_amdgcn_s_barrier()
#define WAIT_LGKM0() asm volatile("s_waitcnt lgkmcnt(0)" ::: "memory")
#define WAIT_VM4() asm volatile("s_waitcnt vmcnt(4)" ::: "memory")
#define WAIT_VM0() asm volatile("s_waitcnt vmcnt(0)" ::: "memory")
#define PRIO(x) __builtin_amdgcn_s_setprio(x)

// register-fragment loads (compile-time array indices only — rule 20)
#define LDA(BUF, MH) do { \
    _Pragma("unroll") for (int m_ = 0; m_ < 4; ++m_) \
    _Pragma("unroll") for (int kk_ = 0; kk_ < 2; ++kk_) \
        a_frag[m_][kk_] = *(const bf16x8*)(lds0 + (((BUF)*2 + 0)*2 + (MH))*8192 \
            + (a_lr + m_*16)*64 + (((kk_*4 + khi) ^ lanelo) << 3)); \
} while (0)

#define LDB(BUF, NH) do { \
    _Pragma("unroll") for (int n_ = 0; n_ < 2; ++n_) \
    _Pragma("unroll") for (int kk_ = 0; kk_ < 2; ++kk_) \
        b_frag[NH][n_][kk_] = *(const bf16x8*)(lds0 + (((BUF)*2 + 1)*2 + (NH))*8192 \
            + (b_lr + n_*16)*64 + (((kk_*4 + khi) ^ lanelo) << 3)); \
} while (0)

#define MM(MH, NH) do { \
    _Pragma("unroll") for (int kk_ = 0; kk_ < 2; ++kk_) \
    _Pragma("unroll") for (int m_ = 0; m_ < 4; ++m_) \
    _Pragma("unroll") for (int n_ = 0; n_ < 2; ++n_) \
        acc[(MH)*4 + m_][(NH)*2 + n_] = __builtin_amdgcn_mfma_f32_16x16x32_bf16( \
            a_frag[m_][kk_], b_frag[NH][n_][kk_], acc[(MH)*4 + m_][(NH)*2 + n_], 0, 0, 0); \
} while (0)

__global__ __launch_bounds__(512, 2) void gemm_tri8(const unsigned short* __restrict__ Aw,
                                                    const unsigned short* __restrict__ Bt,
                                                    float* __restrict__ C) {
    int bid = blockIdx.x;                        // 0 .. 527, longest-K first (LPT)
    int s = (int)((sqrtf(8.0f * (float)bid + 1.0f) - 1.0f) * 0.5f);
    while ((s + 1) * (s + 2) / 2 <= bid) ++s;
    while (s * (s + 1) / 2 > bid) --s;
    int tib = bid - s * (s + 1) / 2;
    int tjb = tib + (31 - s);

    // [dbuf][A=0/B=1][half][128 rows][64 k] bf16 = 128 KiB
    __shared__ __align__(16) unsigned short lds[2][2][2][128][64];
    unsigned short* lds0 = &lds[0][0][0][0][0];

    int t = threadIdx.x;
    int lane = t & 63, w = t >> 6;               // 8 waves: wr in {0,1}, wc in {0..3}
    int wr = w >> 2, wc = w & 3;
    int lanelo = lane & 7, khi = lane >> 4;
    int a_lr = wr * 64 + (lane & 15);
    int b_lr = wc * 32 + (lane & 15);

    int kstart = tib * 256;
    int nkt = (tjb - tib + 1) * 4;               // BK=64 K-tiles (multiple of 4)
    int nit = nkt >> 1;

    // staging geometry: thread covers row (w*8 + lane>>3) (+q*64), swizzled source granule
    int srow = w * 8 + (lane >> 3);
    int sg = ((lane & 7) ^ (lane >> 3)) * 8;
    const unsigned short* gA = Aw + (size_t)(tib * 256 + srow) * ND + sg;
    const unsigned short* gB = Bt + (size_t)(tjb * 256 + srow) * ND + sg;
    unsigned short* sdst = lds0 + (w * 512 + lane * 8);

    auto STAGE = [&](int ab, int buf, int h, int ktg) {
        const unsigned short* g = (ab ? gB : gA) + (size_t)(h * 128) * ND + (kstart + ktg * 64);
        unsigned short* l = sdst + ((buf * 2 + ab) * 2 + h) * 8192;
        gld_lds16(g, l);
        gld_lds16(g + (size_t)64 * ND, l + 4096);
    };

    f32x4 acc[8][4];
#pragma unroll
    for (int m = 0; m < 8; ++m)
#pragma unroll
        for (int n = 0; n < 4; ++n) acc[m][n] = (f32x4){0.f, 0.f, 0.f, 0.f};

    bf16x8 a_frag[4][2];
    bf16x8 b_frag[2][2][2];

    // ---- prologue: kt0 fully + kt1 A0,B0; leave kt1's 2 half-tiles in flight ----
    STAGE(0, 0, 0, 0); STAGE(1, 0, 0, 0); STAGE(0, 0, 1, 0); STAGE(1, 0, 1, 0);
    STAGE(0, 1, 0, 1); STAGE(1, 1, 0, 1);
    WAIT_VM4();
    BAR();

    for (int I = 0; I < nit; ++I) {
        int k1 = 2 * I + 1, k2 = 2 * I + 2, k3 = 2 * I + 3;
        bool s23 = (k2 < nkt);

        // p0: compute kt0 quad(0,0) from buf0; stage kt1.A1 -> buf1
        LDA(0, 0); LDB(0, 0);
        STAGE(0, 1, 1, k1);
        BAR(); WAIT_LGKM0(); PRIO(1); MM(0, 0); PRIO(0); BAR();
        // p1: quad(0,1); stage kt1.B1 -> buf1
        LDB(0, 1);
        STAGE(1, 1, 1, k1);
        BAR(); WAIT_LGKM0(); PRIO(1); MM(0, 1); PRIO(0); BAR();
        // p2: quad(1,0); stage kt2.A0 -> buf0
        LDA(0, 1);
        if (s23) STAGE(0, 0, 0, k2);
        BAR(); WAIT_LGKM0(); PRIO(1); MM(1, 0); PRIO(0); BAR();
        // p3: quad(1,1); stage kt2.B0 -> buf0; counted vmcnt before trailing barrier
        if (s23) STAGE(1, 0, 0, k2);
        BAR(); PRIO(1); MM(1, 1); PRIO(0);
        if (s23) { WAIT_VM4(); } else { WAIT_VM0(); }
        BAR();
        // p4: compute kt1 quad(0,0) from buf1; stage kt2.A1 -> buf0
        LDA(1, 0); LDB(1, 0);
        if (s23) STAGE(0, 0, 1, k2);
        BAR(); WAIT_LGKM0(); PRIO(1); MM(0, 0); PRIO(0); BAR();
        // p5: quad(0,1); stage kt2.B1 -> buf0
        LDB(1, 1);
        if (s23) STAGE(1, 0, 1, k2);
        BAR(); WAIT_LGKM0(); PRIO(1); MM(0, 1); PRIO(0); BAR();
        // p6: quad(1,0); stage kt3.A0 -> buf1
        LDA(1, 1);
        if (s23) STAGE(0, 1, 0, k3);
        BAR(); WAIT_LGKM0(); PRIO(1); MM(1, 0); PRIO(0); BAR();
        // p7: quad(1,1); stage kt3.B0 -> buf1; counted vmcnt
        if (s23) STAGE(1, 1, 0, k3);
        BAR(); PRIO(1); MM(1, 1); PRIO(0); WAIT_VM4(); BAR();
    }

    // ---- epilogue: C/D layout col=lane&15, row=(lane>>4)*4+e ----
#pragma unroll
    for (int mh = 0; mh < 2; ++mh)
#pragma unroll
        for (int m = 0; m < 4; ++m)
#pragma unroll
            for (int nh = 0; nh < 2; ++nh)
#pragma unroll
                for (int n = 0; n < 2; ++n) {
                    f32x4 v = acc[mh * 4 + m][nh * 2 + n];
                    int row0 = tib * 256 + mh * 128 + wr * 64 + m * 16 + (lane >> 4) * 4;
                    int col  = tjb * 256 + nh * 128 + wc * 32 + n * 16 + (lane & 15);
#pragma unroll
                    for (int e = 0; e < 4; ++e)
                        C[(size_t)(row0 + e) * ND + col] = v[e];
                }
}

// ---------------- fallback (only if ws too small): slow but correct ----------------
__global__ void tri_naive(const float* __restrict__ A, const float* __restrict__ B,
                          float* __restrict__ C) {
    int j = blockIdx.x * 64 + (threadIdx.x & 63);
    int i = blockIdx.y * 4 + (threadIdx.x >> 6);
    float s = 0.f;
    if (j >= i) {
        for (int k = i; k <= j; ++k) s += A[(size_t)i * ND + k] * B[(size_t)k * ND + j];
        C[(size_t)i * ND + j] = s;
    } else {
        C[(size_t)i * ND + j] = 0.f;
    }
}

extern "C" void kernel_launch(void* const* d_in, const int* in_sizes, int n_in,
                              void* d_out, int out_size, void* d_ws, size_t ws_size,
                              hipStream_t stream) {
    (void)in_sizes; (void)n_in; (void)out_size;
    const float* A = (const float*)d_in[0];
    const float* B = (const float*)d_in[1];
    float* C = (float*)d_out;

    const size_t halfws = (size_t)ND * ND * sizeof(unsigned short);  // 128 MiB
    if (ws_size >= 2 * halfws) {
        unsigned short* Aw = (unsigned short*)d_ws;
        unsigned short* Bt = (unsigned short*)((char*)d_ws + halfws);

        conv_a<<<dim3(ND * (ND / 8) / 256), dim3(256), 0, stream>>>(A, Aw);
        conv_bt<<<dim3(ND / 64, ND / 64), dim3(256), 0, stream>>>(B, Bt);
        zero_lower<<<dim3(2016), dim3(256), 0, stream>>>(C);
        gemm_tri8<<<dim3(528), dim3(512), 0, stream>>>(Aw, Bt, C);
    } else {
        tri_naive<<<dim3(ND / 64, ND / 4), dim3(256), 0, stream>>>(A, B, C);
    }
}